// Round 7
// baseline (421.333 us; speedup 1.0000x reference)
//
#include <hip/hip_runtime.h>
#include <hip/hip_fp16.h>
#include <math.h>

// ---------------------------------------------------------------------------
// VariationalGCNEncoder: N=50000, E=800000, 128 -> 64 -> {32,32}
// R18: CSR build collapsed into the bucket kernel itself (3 dispatches total).
//      R17 post-mortem: phaseBG's rolled column-sum exposed ~200cy L2 latency
//      per iteration (77us, VALU 4.8%). Instead of fixing the aggregation,
//      delete the need for it: dst (3.2MB) fits every XCD's L2, so each
//      bucket-block SCANS dst directly (coalesced int4; ~25 blocks/XCD share
//      the L2-resident copy), collects its ~4096 matches in LDS, then does
//      hist/scan/dinv/edge-emit + the fused MFMA gemm. Global edge prefix
//      eliminated via per-bucket fixed regions (edges[bx*CAPB..]) and a
//      per-bucket row_ptr table rp2[bx*257+t]. No scatter kernel, no memset,
//      no recs buffer. Gathers verbatim from R14/R16 (rp2 indexing only).
// Pipeline (3 dispatches):
//   buildg:  scan-filter -> CSR(row_ptr2,dinv,edges) -> hp = dinv*(x@W1)
//   gather1: hm = dinv * relu(dinv*(sum hp[src] + hp[n]) + b1)      bf16
//   gather2: out = dinv*(sum hm[src] + hm[n]) @ [Wmu|Wls] + bias    f32
// ---------------------------------------------------------------------------

typedef unsigned int uint;
typedef unsigned short ushort;
typedef __attribute__((ext_vector_type(8))) short short8;   // 8 bf16 = 4 VGPR
typedef __attribute__((ext_vector_type(4))) float f32x4;    // MFMA acc

#define CAPB 5120   // per-bucket edge capacity (mean 4096, sigma 64: 16 sigma)

__device__ __forceinline__ ushort f2bf(float x) {          // f32 -> bf16 RNE
    uint u = __float_as_uint(x);
    u += 0x7fffu + ((u >> 16) & 1u);
    return (ushort)(u >> 16);
}
__device__ __forceinline__ float bf2f(ushort h) {
    return __uint_as_float((uint)h << 16);
}

// ---- fused build: one block per bucket (256 contiguous nodes) -------------
// Phase 1: scan ALL of dst (L2-resident, coalesced). Matches (dst>>8 == bx)
//          pushed to LDS as edgeidx(24b) | dstlow(8b)<<24; LDS hist on dstlow.
// Phase 2: scan -> rp2 (per-bucket row_ptr) + dinv; scattered src loads emit
//          u16 edges into this bucket's fixed region.
// Phase 3: gemm hp[bucket rows] = dinv * (bf16(x) @ bf16(W1)); W1 staged
//          bf16-transposed in LDS (reusing the match buffer).
__global__ __launch_bounds__(256, 2) void k_buildg(
        const int* __restrict__ src, const int* __restrict__ dst,
        const float* __restrict__ x, const float* __restrict__ W1,
        int* __restrict__ rp2, float* __restrict__ dinv,
        ushort* __restrict__ edges, ushort* __restrict__ hp,
        int N, int E, int NBUCK) {
    __shared__ int h[256];
    __shared__ int p[256];
    __shared__ float sdinv[256];
    __shared__ int cnt;
    __shared__ __align__(16) char ubuf[20480];   // marr (20KB) / Wt (17.4KB)
    uint* marr = (uint*)ubuf;
    const int tid = threadIdx.x;
    const int bx  = blockIdx.x;
    h[tid] = 0;
    if (tid == 0) cnt = 0;
    __syncthreads();
    // -- phase 1: filter-scan dst (int4 coalesced; L2-shared across blocks) --
    const int E4 = E >> 2;
    for (int i4 = tid; i4 < E4; i4 += 256) {
        const int4 d4 = ((const int4*)dst)[i4];
        const int i0 = i4 * 4;
        int d;
        d = d4.x; if ((d >> 8) == bx) { int ix = atomicAdd(&cnt, 1); atomicAdd(&h[d & 255], 1); if (ix < CAPB) marr[ix] = (uint)(i0    ) | ((uint)(d & 255) << 24); }
        d = d4.y; if ((d >> 8) == bx) { int ix = atomicAdd(&cnt, 1); atomicAdd(&h[d & 255], 1); if (ix < CAPB) marr[ix] = (uint)(i0 + 1) | ((uint)(d & 255) << 24); }
        d = d4.z; if ((d >> 8) == bx) { int ix = atomicAdd(&cnt, 1); atomicAdd(&h[d & 255], 1); if (ix < CAPB) marr[ix] = (uint)(i0 + 2) | ((uint)(d & 255) << 24); }
        d = d4.w; if ((d >> 8) == bx) { int ix = atomicAdd(&cnt, 1); atomicAdd(&h[d & 255], 1); if (ix < CAPB) marr[ix] = (uint)(i0 + 3) | ((uint)(d & 255) << 24); }
    }
    for (int i = E4 * 4 + tid; i < E; i += 256) {        // tail (E%4)
        int d = dst[i];
        if ((d >> 8) == bx) { int ix = atomicAdd(&cnt, 1); atomicAdd(&h[d & 255], 1); if (ix < CAPB) marr[ix] = (uint)i | ((uint)(d & 255) << 24); }
    }
    __syncthreads();
    // -- phase 2: scan hist -> rp2/dinv; emit u16 edges ----------------------
    int v = h[tid];
    p[tid] = v;
    __syncthreads();
    #pragma unroll
    for (int off = 1; off < 256; off <<= 1) {
        int xv = (tid >= off) ? p[tid - off] : 0;
        __syncthreads();
        p[tid] += xv;
        __syncthreads();
    }
    const int excl = p[tid] - v;
    const int node = bx * 256 + tid;
    const float dvt = rsqrtf((float)(v + 1));
    sdinv[tid] = dvt;
    rp2[bx * 257 + tid] = bx * CAPB + excl;
    if (tid == 255) rp2[bx * 257 + 256] = bx * CAPB + excl + v;
    if (node < N) dinv[node] = dvt;
    h[tid] = excl;                              // reuse as local cursor
    __syncthreads();
    const int c = min(cnt, CAPB);
    for (int j = tid; j < c; j += 256) {
        const uint r = marr[j];
        const int s = src[r & 0xffffff];        // scattered 4B (pipelined/waves)
        const int pos = atomicAdd(&h[r >> 24], 1);
        if (pos < CAPB) edges[(size_t)bx * CAPB + pos] = (ushort)s;
    }
    __syncthreads();                            // marr reads done
    // -- phase 3: gemm for this bucket's 256 rows ---------------------------
    ushort (*Wt)[136] = (ushort(*)[136])ubuf;   // col-major bf16, stride 272B
    #pragma unroll
    for (int it = 0; it < 8; ++it) {            // 8192 elems, 32/thread
        int idx = (it * 256 + tid) * 4;
        int k = idx >> 6, ccol = idx & 63;
        float4 wv = *(const float4*)(W1 + idx);
        Wt[ccol + 0][k] = f2bf(wv.x);
        Wt[ccol + 1][k] = f2bf(wv.y);
        Wt[ccol + 2][k] = f2bf(wv.z);
        Wt[ccol + 3][k] = f2bf(wv.w);
    }
    __syncthreads();
    const int w = tid >> 6, l = tid & 63;
    const int m = l & 15, q = l >> 4;
    #pragma unroll 1
    for (int t = 0; t < 4; ++t) {               // 4 tiles of 64 rows
        const int lrow0 = t * 64 + w * 16;
        const int row0  = bx * 256 + lrow0;
        const size_t arow = (size_t)min(row0 + m, N - 1);
        f32x4 acc0 = {0.f, 0.f, 0.f, 0.f}, acc1 = acc0, acc2 = acc0, acc3 = acc0;
        #pragma unroll
        for (int kc = 0; kc < 4; ++kc) {
            const int kofs = kc * 32 + q * 8;
            const float4* xr = (const float4*)(x + arow * 128 + kofs);
            float4 xa = xr[0], xb = xr[1];
            short8 a;
            a[0] = (short)f2bf(xa.x); a[1] = (short)f2bf(xa.y);
            a[2] = (short)f2bf(xa.z); a[3] = (short)f2bf(xa.w);
            a[4] = (short)f2bf(xb.x); a[5] = (short)f2bf(xb.y);
            a[6] = (short)f2bf(xb.z); a[7] = (short)f2bf(xb.w);
            short8 b0 = *(const short8*)&Wt[m][kofs];
            short8 b1 = *(const short8*)&Wt[m + 16][kofs];
            short8 b2 = *(const short8*)&Wt[m + 32][kofs];
            short8 b3 = *(const short8*)&Wt[m + 48][kofs];
            acc0 = __builtin_amdgcn_mfma_f32_16x16x32_bf16(a, b0, acc0, 0, 0, 0);
            acc1 = __builtin_amdgcn_mfma_f32_16x16x32_bf16(a, b1, acc1, 0, 0, 0);
            acc2 = __builtin_amdgcn_mfma_f32_16x16x32_bf16(a, b2, acc2, 0, 0, 0);
            acc3 = __builtin_amdgcn_mfma_f32_16x16x32_bf16(a, b3, acc3, 0, 0, 0);
        }
        #pragma unroll
        for (int r = 0; r < 4; ++r) {           // D: row=q*4+r, col=g*16+m
            int lrow = lrow0 + q * 4 + r;
            int row  = bx * 256 + lrow;
            if (row >= N) continue;
            float dv = sdinv[lrow];
            ushort* hr = hp + (size_t)row * 64 + m;
            hr[0]  = f2bf(acc0[r] * dv);
            hr[16] = f2bf(acc1[r] * dv);
            hr[32] = f2bf(acc2[r] * dv);
            hr[48] = f2bf(acc3[r] * dv);
        }
    }
}

// ---- 8-lane-group gather: group owns one node; lane owns 8 features ----
// Per 8-edge chunk: one coalesced edges load (2B/lane), then 8 row loads
// (8 lanes x uint4 = one 128B line each), all independent -> 8 rows in
// flight per group, 64 per wave. No cross-lane reduce (features disjoint).
__device__ __forceinline__ void gather_grp8(
        const uint* __restrict__ hp, const ushort* __restrict__ edges,
        int beg, int end, int ECAP, int sl, float4& a0, float4& a1) {
    for (int base = beg; base < end; base += 8) {
        const int mrec = (int)edges[min(base + sl, ECAP - 1)];
        const int cnt = end - base;
        if (cnt >= 8) {
            #pragma unroll
            for (int i = 0; i < 8; ++i) {
                const int r = __shfl(mrec, i, 8);
                const uint4 v = *(const uint4*)(hp + (size_t)r * 32 + 4 * sl);
                a0.x += __uint_as_float(v.x << 16);
                a0.y += __uint_as_float(v.x & 0xffff0000u);
                a0.z += __uint_as_float(v.y << 16);
                a0.w += __uint_as_float(v.y & 0xffff0000u);
                a1.x += __uint_as_float(v.z << 16);
                a1.y += __uint_as_float(v.z & 0xffff0000u);
                a1.z += __uint_as_float(v.w << 16);
                a1.w += __uint_as_float(v.w & 0xffff0000u);
            }
        } else {
            #pragma unroll
            for (int i = 0; i < 7; ++i) {     // cnt in 1..7; dups are L1 hits
                const int r = __shfl(mrec, min(i, cnt - 1), 8);
                uint4 v = *(const uint4*)(hp + (size_t)r * 32 + 4 * sl);
                if (i >= cnt) { v.x = 0u; v.y = 0u; v.z = 0u; v.w = 0u; }
                a0.x += __uint_as_float(v.x << 16);
                a0.y += __uint_as_float(v.x & 0xffff0000u);
                a0.z += __uint_as_float(v.y << 16);
                a0.w += __uint_as_float(v.y & 0xffff0000u);
                a1.x += __uint_as_float(v.z << 16);
                a1.y += __uint_as_float(v.z & 0xffff0000u);
                a1.z += __uint_as_float(v.w << 16);
                a1.w += __uint_as_float(v.w & 0xffff0000u);
            }
        }
    }
}

// hm[n] = dinv * relu( dinv * (sum hp[src] + hp[n]) + b1 )   (bf16x2)
__global__ __launch_bounds__(256, 6) void k_gather1(
        const uint* __restrict__ hp, const int* __restrict__ rp2,
        const ushort* __restrict__ edges, const float* __restrict__ dinv,
        const float* __restrict__ b1, uint* __restrict__ ho, int N, int ECAP) {
    const int lane = threadIdx.x & 63;
    const int sl = lane & 7;
    const int n = blockIdx.x * 32 + ((threadIdx.x >> 6) << 3) + (lane >> 3);
    const int nc = min(n, N - 1);
    const int beg = rp2[(nc >> 8) * 257 + (nc & 255)];
    const int end = rp2[(nc >> 8) * 257 + (nc & 255) + 1];
    float4 a0 = {0.f, 0.f, 0.f, 0.f}, a1 = a0;
    gather_grp8(hp, edges, beg, end, ECAP, sl, a0, a1);
    const float dv = dinv[nc];
    const uint4 sv = *(const uint4*)(hp + (size_t)nc * 32 + 4 * sl);  // self
    const float4 bA = ((const float4*)b1)[2 * sl];
    const float4 bB = ((const float4*)b1)[2 * sl + 1];
    float s0 = a0.x + bf2f((ushort)sv.x);
    float s1 = a0.y + bf2f((ushort)(sv.x >> 16));
    float s2 = a0.z + bf2f((ushort)sv.y);
    float s3 = a0.w + bf2f((ushort)(sv.y >> 16));
    float s4 = a1.x + bf2f((ushort)sv.z);
    float s5 = a1.y + bf2f((ushort)(sv.z >> 16));
    float s6 = a1.z + bf2f((ushort)sv.w);
    float s7 = a1.w + bf2f((ushort)(sv.w >> 16));
    float h0 = fmaxf(fmaf(dv, s0, bA.x), 0.f) * dv;   // relu then pre-scale
    float h1 = fmaxf(fmaf(dv, s1, bA.y), 0.f) * dv;
    float h2 = fmaxf(fmaf(dv, s2, bA.z), 0.f) * dv;
    float h3 = fmaxf(fmaf(dv, s3, bA.w), 0.f) * dv;
    float h4 = fmaxf(fmaf(dv, s4, bB.x), 0.f) * dv;
    float h5 = fmaxf(fmaf(dv, s5, bB.y), 0.f) * dv;
    float h6 = fmaxf(fmaf(dv, s6, bB.z), 0.f) * dv;
    float h7 = fmaxf(fmaf(dv, s7, bB.w), 0.f) * dv;
    if (n < N) {
        uint4 o;
        o.x = (uint)f2bf(h0) | ((uint)f2bf(h1) << 16);
        o.y = (uint)f2bf(h2) | ((uint)f2bf(h3) << 16);
        o.z = (uint)f2bf(h4) | ((uint)f2bf(h5) << 16);
        o.w = (uint)f2bf(h6) | ((uint)f2bf(h7) << 16);
        *(uint4*)(ho + (size_t)n * 32 + 4 * sl) = o;
    }
}

// g = dinv*(sum hm[src] + hm[n]);  out[n] = g @ [Wmu|Wls] + bias
__global__ __launch_bounds__(256, 6) void k_gather2(
        const uint* __restrict__ hp, const int* __restrict__ rp2,
        const ushort* __restrict__ edges, const float* __restrict__ dinv,
        const float* __restrict__ Wmu, const float* __restrict__ Wls,
        const float* __restrict__ bmu, const float* __restrict__ bls,
        float* __restrict__ out, int N, int ECAP) {
    __shared__ __align__(16) float hs[4][8][64];   // [wave][group-node][feat]
    const int lane = threadIdx.x & 63;
    const int sl = lane & 7, grp = lane >> 3;
    const int w = threadIdx.x >> 6;
    const int n = blockIdx.x * 32 + (w << 3) + grp;
    const int nc = min(n, N - 1);
    const int beg = rp2[(nc >> 8) * 257 + (nc & 255)];
    const int end = rp2[(nc >> 8) * 257 + (nc & 255) + 1];
    float4 a0 = {0.f, 0.f, 0.f, 0.f}, a1 = a0;
    gather_grp8(hp, edges, beg, end, ECAP, sl, a0, a1);
    const float dv = dinv[nc];
    const uint4 sv = *(const uint4*)(hp + (size_t)nc * 32 + 4 * sl);
    float4 gA, gB;
    gA.x = dv * (a0.x + bf2f((ushort)sv.x));
    gA.y = dv * (a0.y + bf2f((ushort)(sv.x >> 16)));
    gA.z = dv * (a0.z + bf2f((ushort)sv.y));
    gA.w = dv * (a0.w + bf2f((ushort)(sv.y >> 16)));
    gB.x = dv * (a1.x + bf2f((ushort)sv.z));
    gB.y = dv * (a1.y + bf2f((ushort)(sv.z >> 16)));
    gB.z = dv * (a1.z + bf2f((ushort)sv.w));
    gB.w = dv * (a1.w + bf2f((ushort)(sv.w >> 16)));
    *(float4*)&hs[w][grp][8 * sl]     = gA;        // wave-local LDS: no barrier
    *(float4*)&hs[w][grp][8 * sl + 4] = gB;
    // epilogue: out_row = g @ [Wmu|Wls] + bias for the wave's 8 nodes,
    // two passes of 4 nodes; W column loads hoisted; hs reads broadcast.
    const float* Wsel = (lane < 32) ? (Wmu + lane) : (Wls + (lane - 32));
    const float bias  = (lane < 32) ? bmu[lane] : bls[lane - 32];
    #pragma unroll
    for (int p = 0; p < 2; ++p) {
        float c0 = 0.f, c1 = 0.f, c2 = 0.f, c3 = 0.f;
        #pragma unroll 4
        for (int k = 0; k < 64; ++k) {
            float wv = Wsel[k * 32];
            c0 = fmaf(hs[w][p * 4 + 0][k], wv, c0);
            c1 = fmaf(hs[w][p * 4 + 1][k], wv, c1);
            c2 = fmaf(hs[w][p * 4 + 2][k], wv, c2);
            c3 = fmaf(hs[w][p * 4 + 3][k], wv, c3);
        }
        const int n0 = blockIdx.x * 32 + (w << 3) + p * 4;
        float cs[4] = {c0, c1, c2, c3};
        #pragma unroll
        for (int gg = 0; gg < 4; ++gg) {
            int nn = n0 + gg;
            if (nn >= N) break;
            float t = cs[gg] + bias;
            if (lane < 32) out[(size_t)nn * 32 + lane] = t;
            else           out[(size_t)N * 32 + (size_t)nn * 32 + (lane - 32)] = t;
        }
    }
}

extern "C" void kernel_launch(void* const* d_in, const int* in_sizes, int n_in,
                              void* d_out, int out_size, void* d_ws, size_t ws_size,
                              hipStream_t stream) {
    const float* x   = (const float*)d_in[0];
    const int*   ei  = (const int*)d_in[1];
    const float* W1  = (const float*)d_in[2];
    const float* b1  = (const float*)d_in[3];
    const float* Wmu = (const float*)d_in[4];
    const float* bmu = (const float*)d_in[5];
    const float* Wls = (const float*)d_in[6];
    const float* bls = (const float*)d_in[7];
    float* out = (float*)d_out;

    const int N = in_sizes[0] / 128;          // 50000  (< 65536: u16 src pack)
    const int E = in_sizes[1] / 2;            // 800000
    const int* src = ei;
    const int* dst = ei + E;
    const int NBUCK = (N + 255) / 256;        // buckets / buildg blocks (196)
    const int NG    = (N + 31) / 32;          // gather blocks (32 nodes/block)
    const int ECAP  = NBUCK * CAPB;           // edges array capacity

    char* w = (char*)d_ws;
    auto carve = [&](size_t bytes) { char* p = w; w += (bytes + 1023) & ~(size_t)1023; return p; };
    int*    rp2     = (int*)   carve((size_t)NBUCK * 257 * 4);   // row_ptr table
    float*  dinv    = (float*) carve((size_t)N * 4);
    ushort* edges   = (ushort*)carve((size_t)ECAP * 2);          // u16 src records
    ushort* h_pre   = (ushort*)carve((size_t)N * 64 * 2);        // bf16 pre-scaled
    ushort* h_mid   = (ushort*)carve((size_t)N * 64 * 2);        // bf16 pre-scaled

    k_buildg  <<<NBUCK, 256, 0, stream>>>(src, dst, x, W1, rp2, dinv,
                                          edges, h_pre, N, E, NBUCK);
    k_gather1 <<<NG, 256, 0, stream>>>((const uint*)h_pre, rp2, edges, dinv,
                                       b1, (uint*)h_mid, N, ECAP);
    k_gather2 <<<NG, 256, 0, stream>>>((const uint*)h_mid, rp2, edges, dinv,
                                       Wmu, Wls, bmu, bls, out, N, ECAP);
}

// Round 9
// 207.599 us; speedup vs baseline: 2.0296x; 2.0296x over previous
//
#include <hip/hip_runtime.h>
#include <hip/hip_fp16.h>
#include <math.h>

// ---------------------------------------------------------------------------
// VariationalGCNEncoder: N=50000, E=800000, 128 -> 64 -> {32,32}
// R19b: R19 with the compile fix (nontemporal stores use scalar uints; HIP's
//      uint2 class type is rejected by __builtin_nontemporal_store).
//      (a) R17's no-memset deterministic-cell scatter kept; phaseBG
//      aggregation FIXED: cell counts loaded one-per-thread (391 parallel
//      loads = one L2 latency round; R17's serial column-sum was 391 rounds),
//      LDS 512-scan, padded cooperative cell copy (flat-slot loop, fully
//      pipelined). Per-bucket fixed edge regions + rp2 table (R18, validated)
//      kill the global prefix scan.
//      (b) gathers: hp/hm stored as 3.2MB per-half arrays; each gather kernel
//      processes half A for its nodes then half B IN ONE KERNEL (R15's split
//      without the +2 dispatches). Per phase the resident set fits a 4MB XCD
//      L2. nontemporal loads (edges) + stores (mid/out) keep the streams from
//      evicting it (the R15 failure mode). g2 accumulates both halves' g in
//      LDS; epilogue order k=0..63 unchanged (absmax preserved).
// Pipeline (4 dispatches):
//   scatter -> phaseBG(CSR + MFMA gemm -> hpA|hpB)
//   gather1: midA|midB = dinv*relu(dinv*(sum hp[src]+self)+b1)     bf16
//   gather2: out = dinv*(sum mid[src]+self) @ [Wmu|Wls] + bias     f32
// ---------------------------------------------------------------------------

typedef unsigned int uint;
typedef unsigned short ushort;
typedef __attribute__((ext_vector_type(8))) short short8;   // 8 bf16 = 4 VGPR
typedef __attribute__((ext_vector_type(4))) float f32x4;    // MFMA acc

#define CAPC 48     // per (scatter-block,bucket) cell capacity (~1e-12 tail)
#define CAPB 5120   // per-bucket edge region (mean 4096, sigma 64)

__device__ __forceinline__ ushort f2bf(float x) {          // f32 -> bf16 RNE
    uint u = __float_as_uint(x);
    u += 0x7fffu + ((u >> 16) & 1u);
    return (ushort)(u >> 16);
}
__device__ __forceinline__ float bf2f(ushort h) {
    return __uint_as_float((uint)h << 16);
}

// ---- scatter: deterministic per-(block,bucket) cells, no memset needed ----
// rec = src(16) | dstlow(8)<<16 | bucket(8)<<24 ; bucket = dst>>8
__global__ __launch_bounds__(256) void k_scatter(
        const int* __restrict__ src, const int* __restrict__ dst,
        int* __restrict__ cmat, uint* __restrict__ recs, int E, int SB) {
    __shared__ int h[256];
    const int tid = threadIdx.x;
    const int bx  = blockIdx.x;
    h[tid] = 0;
    __syncthreads();
    const int base = bx * 2048;
    uint rec[8]; int rk[8];
    #pragma unroll
    for (int k = 0; k < 8; ++k) {
        int i = base + k * 256 + tid;
        if (i < E) {
            int s = __builtin_nontemporal_load(src + i);
            int d = __builtin_nontemporal_load(dst + i);
            int b = d >> 8;
            rec[k] = (uint)s | ((uint)(d & 255) << 16) | ((uint)b << 24);
            rk[k] = atomicAdd(&h[b], 1);
        }
    }
    __syncthreads();
    cmat[bx * 256 + tid] = h[tid];            // always written (no poison)
    #pragma unroll
    for (int k = 0; k < 8; ++k) {
        int i = base + k * 256 + tid;
        if (i < E) {
            int b = rec[k] >> 24;
            if (rk[k] < CAPC)
                recs[((size_t)b * SB + bx) * CAPC + rk[k]] = rec[k];
        }
    }
}

// ---- phaseB + gemm: one block per bucket (256 contiguous nodes) -----------
// 1. cell counts: ONE load per thread (parallel; R17's serial loop was the
//    77us bug), LDS 512-scan -> per-cell offsets + total.
// 2. padded cooperative copy cells -> rstage (LDS) with fused dstlow hist.
// 3. dstlow scan -> rp2 (per-bucket row_ptr) + dinv; u16 edge emit into this
//    bucket's fixed region edges[bx*CAPB..].
// 4. gemm: hpA|hpB[bucket rows] = dinv * (bf16(x) @ bf16(W1)); W1 staged
//    bf16-transposed in LDS (reusing rstage).
__global__ __launch_bounds__(256, 2) void k_phaseBG(
        const uint* __restrict__ recs, const int* __restrict__ cmat,
        const float* __restrict__ x, const float* __restrict__ W1,
        int* __restrict__ rp2, float* __restrict__ dinv,
        ushort* __restrict__ edges, ushort* __restrict__ hpA,
        ushort* __restrict__ hpB, int N, int NBUCK, int SB) {
    __shared__ int h[256];
    __shared__ int p[256];
    __shared__ float sdinv[256];
    __shared__ int cc[512];
    __shared__ int co[512];
    __shared__ int lowTot, scnt;
    __shared__ __align__(16) char ubuf[20480];   // rstage (20KB) / Wt (17.4KB)
    uint* rstage = (uint*)ubuf;
    const int tid = threadIdx.x;
    const int bx  = blockIdx.x;
    h[tid] = 0;
    // -- 1. cell counts (parallel loads) + 512-scan -------------------------
    cc[tid]       = (tid < SB)       ? min(cmat[tid * 256 + bx], CAPC) : 0;
    cc[tid + 256] = (tid + 256 < SB) ? min(cmat[(tid + 256) * 256 + bx], CAPC) : 0;
    __syncthreads();
    int v = cc[tid];
    p[tid] = v;
    __syncthreads();
    #pragma unroll
    for (int off = 1; off < 256; off <<= 1) {
        int xv = (tid >= off) ? p[tid - off] : 0;
        __syncthreads();
        p[tid] += xv;
        __syncthreads();
    }
    co[tid] = p[tid] - v;
    if (tid == 255) lowTot = p[255];
    __syncthreads();
    v = cc[tid + 256];
    p[tid] = v;
    __syncthreads();
    #pragma unroll
    for (int off = 1; off < 256; off <<= 1) {
        int xv = (tid >= off) ? p[tid - off] : 0;
        __syncthreads();
        p[tid] += xv;
        __syncthreads();
    }
    co[tid + 256] = p[tid] - v + lowTot;
    if (tid == 255) scnt = lowTot + p[255];
    __syncthreads();
    // -- 2. padded cooperative copy (independent iterations, pipelined) -----
    const int TOTS = SB * CAPC;
    for (int s = tid; s < TOTS; s += 256) {
        const int sb = s / CAPC, i = s - sb * CAPC;
        if (i < cc[sb]) {
            uint r = __builtin_nontemporal_load(
                         recs + ((size_t)bx * SB + sb) * CAPC + i);
            int d = co[sb] + i;
            if (d < CAPB) {
                rstage[d] = r;
                atomicAdd(&h[(r >> 16) & 255], 1);
            }
        }
    }
    __syncthreads();
    // -- 3. dstlow scan -> rp2/dinv; edge emit ------------------------------
    v = h[tid];
    p[tid] = v;
    __syncthreads();
    #pragma unroll
    for (int off = 1; off < 256; off <<= 1) {
        int xv = (tid >= off) ? p[tid - off] : 0;
        __syncthreads();
        p[tid] += xv;
        __syncthreads();
    }
    const int excl = p[tid] - v;
    const int node = bx * 256 + tid;
    const float dvt = rsqrtf((float)(v + 1));
    sdinv[tid] = dvt;
    rp2[bx * 257 + tid] = bx * CAPB + excl;
    if (tid == 255) rp2[bx * 257 + 256] = bx * CAPB + excl + v;
    if (node < N) dinv[node] = dvt;
    h[tid] = excl;                              // reuse as local cursor
    __syncthreads();
    const int cnt = min(scnt, CAPB);
    for (int i = tid; i < cnt; i += 256) {
        uint r = rstage[i];
        int pos = atomicAdd(&h[(r >> 16) & 255], 1);
        if (pos < CAPB)
            edges[(size_t)bx * CAPB + pos] = (ushort)(r & 0xffffu);
    }
    __syncthreads();                            // rstage reads done
    // -- 4. gemm for this bucket's 256 rows (split hpA|hpB outputs) ---------
    ushort (*Wt)[136] = (ushort(*)[136])ubuf;   // col-major bf16, stride 272B
    #pragma unroll
    for (int it = 0; it < 8; ++it) {            // 8192 elems, 32/thread
        int idx = (it * 256 + tid) * 4;
        int k = idx >> 6, ccol = idx & 63;
        float4 wv = *(const float4*)(W1 + idx);
        Wt[ccol + 0][k] = f2bf(wv.x);
        Wt[ccol + 1][k] = f2bf(wv.y);
        Wt[ccol + 2][k] = f2bf(wv.z);
        Wt[ccol + 3][k] = f2bf(wv.w);
    }
    __syncthreads();
    const int w = tid >> 6, l = tid & 63;
    const int m = l & 15, q = l >> 4;
    #pragma unroll 1
    for (int t = 0; t < 4; ++t) {               // 4 tiles of 64 rows
        const int lrow0 = t * 64 + w * 16;
        const int row0  = bx * 256 + lrow0;
        const size_t arow = (size_t)min(row0 + m, N - 1);
        f32x4 acc0 = {0.f, 0.f, 0.f, 0.f}, acc1 = acc0, acc2 = acc0, acc3 = acc0;
        #pragma unroll
        for (int kc = 0; kc < 4; ++kc) {
            const int kofs = kc * 32 + q * 8;
            const float4* xr = (const float4*)(x + arow * 128 + kofs);
            float4 xa = xr[0], xb = xr[1];
            short8 a;
            a[0] = (short)f2bf(xa.x); a[1] = (short)f2bf(xa.y);
            a[2] = (short)f2bf(xa.z); a[3] = (short)f2bf(xa.w);
            a[4] = (short)f2bf(xb.x); a[5] = (short)f2bf(xb.y);
            a[6] = (short)f2bf(xb.z); a[7] = (short)f2bf(xb.w);
            short8 b0 = *(const short8*)&Wt[m][kofs];
            short8 b1 = *(const short8*)&Wt[m + 16][kofs];
            short8 b2 = *(const short8*)&Wt[m + 32][kofs];
            short8 b3 = *(const short8*)&Wt[m + 48][kofs];
            acc0 = __builtin_amdgcn_mfma_f32_16x16x32_bf16(a, b0, acc0, 0, 0, 0);
            acc1 = __builtin_amdgcn_mfma_f32_16x16x32_bf16(a, b1, acc1, 0, 0, 0);
            acc2 = __builtin_amdgcn_mfma_f32_16x16x32_bf16(a, b2, acc2, 0, 0, 0);
            acc3 = __builtin_amdgcn_mfma_f32_16x16x32_bf16(a, b3, acc3, 0, 0, 0);
        }
        #pragma unroll
        for (int r = 0; r < 4; ++r) {           // D: row=q*4+r, col=g*16+m
            int lrow = lrow0 + q * 4 + r;
            int row  = bx * 256 + lrow;
            if (row >= N) continue;
            float dv = sdinv[lrow];
            ushort* hrA = hpA + (size_t)row * 32 + m;
            hrA[0]  = f2bf(acc0[r] * dv);
            hrA[16] = f2bf(acc1[r] * dv);
            ushort* hrB = hpB + (size_t)row * 32 + m;
            hrB[0]  = f2bf(acc2[r] * dv);
            hrB[16] = f2bf(acc3[r] * dv);
        }
    }
}

// ---- half-row gather: 8-lane group per node; lane owns 4 feats (uint2) ----
// One 3.2MB half-array per phase -> fits a 4MB XCD L2. edges via nt loads
// (streaming; don't evict the resident half).
__device__ __forceinline__ float4 gather_half(
        const uint* __restrict__ rows, const ushort* __restrict__ edges,
        int beg, int end, int ECAP, int sl) {
    float4 a = {0.f, 0.f, 0.f, 0.f};
    for (int base = beg; base < end; base += 8) {
        const int mrec = (int)__builtin_nontemporal_load(
                             edges + min(base + sl, ECAP - 1));
        const int cnt = end - base;
        if (cnt >= 8) {
            #pragma unroll
            for (int i = 0; i < 8; ++i) {
                const int r = __shfl(mrec, i, 8);
                const uint2 v = *(const uint2*)(rows + (size_t)r * 16 + 2 * sl);
                a.x += __uint_as_float(v.x << 16);
                a.y += __uint_as_float(v.x & 0xffff0000u);
                a.z += __uint_as_float(v.y << 16);
                a.w += __uint_as_float(v.y & 0xffff0000u);
            }
        } else {
            #pragma unroll
            for (int i = 0; i < 7; ++i) {     // cnt in 1..7; dups are L1 hits
                const int r = __shfl(mrec, min(i, cnt - 1), 8);
                uint2 v = *(const uint2*)(rows + (size_t)r * 16 + 2 * sl);
                if (i >= cnt) { v.x = 0u; v.y = 0u; }
                a.x += __uint_as_float(v.x << 16);
                a.y += __uint_as_float(v.x & 0xffff0000u);
                a.z += __uint_as_float(v.y << 16);
                a.w += __uint_as_float(v.y & 0xffff0000u);
            }
        }
    }
    return a;
}

// midA|midB[n] = dinv * relu( dinv * (sum hp[src] + hp[n]) + b1 )   per half
__global__ __launch_bounds__(256, 6) void k_gather1(
        const uint* __restrict__ hpA, const uint* __restrict__ hpB,
        const int* __restrict__ rp2, const ushort* __restrict__ edges,
        const float* __restrict__ dinv, const float* __restrict__ b1,
        uint* __restrict__ midA, uint* __restrict__ midB, int N, int ECAP) {
    const int lane = threadIdx.x & 63;
    const int sl = lane & 7;
    const int n = blockIdx.x * 32 + ((threadIdx.x >> 6) << 3) + (lane >> 3);
    const int nc = min(n, N - 1);
    const int beg = rp2[(nc >> 8) * 257 + (nc & 255)];
    const int end = rp2[(nc >> 8) * 257 + (nc & 255) + 1];
    const float dv = dinv[nc];
    // ---- phase A (hpA resident) ----
    {
        float4 a = gather_half(hpA, edges, beg, end, ECAP, sl);
        const uint2 sv = *(const uint2*)(hpA + (size_t)nc * 16 + 2 * sl);
        const float4 b = *(const float4*)(b1 + 4 * sl);
        float s0 = a.x + bf2f((ushort)sv.x);
        float s1 = a.y + bf2f((ushort)(sv.x >> 16));
        float s2 = a.z + bf2f((ushort)sv.y);
        float s3 = a.w + bf2f((ushort)(sv.y >> 16));
        float h0 = fmaxf(fmaf(dv, s0, b.x), 0.f) * dv;
        float h1 = fmaxf(fmaf(dv, s1, b.y), 0.f) * dv;
        float h2 = fmaxf(fmaf(dv, s2, b.z), 0.f) * dv;
        float h3 = fmaxf(fmaf(dv, s3, b.w), 0.f) * dv;
        if (n < N) {
            uint o0 = (uint)f2bf(h0) | ((uint)f2bf(h1) << 16);
            uint o1 = (uint)f2bf(h2) | ((uint)f2bf(h3) << 16);
            uint* dp = midA + (size_t)n * 16 + 2 * sl;
            __builtin_nontemporal_store(o0, dp);
            __builtin_nontemporal_store(o1, dp + 1);
        }
    }
    // ---- phase B (hpB resident) ----
    {
        float4 a = gather_half(hpB, edges, beg, end, ECAP, sl);
        const uint2 sv = *(const uint2*)(hpB + (size_t)nc * 16 + 2 * sl);
        const float4 b = *(const float4*)(b1 + 32 + 4 * sl);
        float s0 = a.x + bf2f((ushort)sv.x);
        float s1 = a.y + bf2f((ushort)(sv.x >> 16));
        float s2 = a.z + bf2f((ushort)sv.y);
        float s3 = a.w + bf2f((ushort)(sv.y >> 16));
        float h0 = fmaxf(fmaf(dv, s0, b.x), 0.f) * dv;
        float h1 = fmaxf(fmaf(dv, s1, b.y), 0.f) * dv;
        float h2 = fmaxf(fmaf(dv, s2, b.z), 0.f) * dv;
        float h3 = fmaxf(fmaf(dv, s3, b.w), 0.f) * dv;
        if (n < N) {
            uint o0 = (uint)f2bf(h0) | ((uint)f2bf(h1) << 16);
            uint o1 = (uint)f2bf(h2) | ((uint)f2bf(h3) << 16);
            uint* dp = midB + (size_t)n * 16 + 2 * sl;
            __builtin_nontemporal_store(o0, dp);
            __builtin_nontemporal_store(o1, dp + 1);
        }
    }
}

// g = dinv*(sum mid[src] + mid[n]) per half -> LDS;  out = g@[Wmu|Wls]+bias
__global__ __launch_bounds__(256, 6) void k_gather2(
        const uint* __restrict__ midA, const uint* __restrict__ midB,
        const int* __restrict__ rp2, const ushort* __restrict__ edges,
        const float* __restrict__ dinv,
        const float* __restrict__ Wmu, const float* __restrict__ Wls,
        const float* __restrict__ bmu, const float* __restrict__ bls,
        float* __restrict__ out, int N, int ECAP) {
    __shared__ __align__(16) float hs[4][8][64];   // [wave][group-node][feat]
    const int lane = threadIdx.x & 63;
    const int sl = lane & 7, grp = lane >> 3;
    const int w = threadIdx.x >> 6;
    const int n = blockIdx.x * 32 + (w << 3) + grp;
    const int nc = min(n, N - 1);
    const int beg = rp2[(nc >> 8) * 257 + (nc & 255)];
    const int end = rp2[(nc >> 8) * 257 + (nc & 255) + 1];
    const float dv = dinv[nc];
    {   // phase A: feats 0..31
        float4 a = gather_half(midA, edges, beg, end, ECAP, sl);
        const uint2 sv = *(const uint2*)(midA + (size_t)nc * 16 + 2 * sl);
        float4 g;
        g.x = dv * (a.x + bf2f((ushort)sv.x));
        g.y = dv * (a.y + bf2f((ushort)(sv.x >> 16)));
        g.z = dv * (a.z + bf2f((ushort)sv.y));
        g.w = dv * (a.w + bf2f((ushort)(sv.y >> 16)));
        *(float4*)&hs[w][grp][4 * sl] = g;         // wave-local LDS
    }
    {   // phase B: feats 32..63
        float4 a = gather_half(midB, edges, beg, end, ECAP, sl);
        const uint2 sv = *(const uint2*)(midB + (size_t)nc * 16 + 2 * sl);
        float4 g;
        g.x = dv * (a.x + bf2f((ushort)sv.x));
        g.y = dv * (a.y + bf2f((ushort)(sv.x >> 16)));
        g.z = dv * (a.z + bf2f((ushort)sv.y));
        g.w = dv * (a.w + bf2f((ushort)(sv.y >> 16)));
        *(float4*)&hs[w][grp][32 + 4 * sl] = g;
    }
    // epilogue: out_row = g @ [Wmu|Wls] + bias, 8 nodes per wave, k=0..63
    // order identical to R16 (absmax preserved). W column loads hoisted.
    const float* Wsel = (lane < 32) ? (Wmu + lane) : (Wls + (lane - 32));
    const float bias  = (lane < 32) ? bmu[lane] : bls[lane - 32];
    #pragma unroll
    for (int p = 0; p < 2; ++p) {
        float c0 = 0.f, c1 = 0.f, c2 = 0.f, c3 = 0.f;
        #pragma unroll 4
        for (int k = 0; k < 64; ++k) {
            float wv = Wsel[k * 32];
            c0 = fmaf(hs[w][p * 4 + 0][k], wv, c0);
            c1 = fmaf(hs[w][p * 4 + 1][k], wv, c1);
            c2 = fmaf(hs[w][p * 4 + 2][k], wv, c2);
            c3 = fmaf(hs[w][p * 4 + 3][k], wv, c3);
        }
        const int n0 = blockIdx.x * 32 + (w << 3) + p * 4;
        float cs[4] = {c0, c1, c2, c3};
        #pragma unroll
        for (int gg = 0; gg < 4; ++gg) {
            int nn = n0 + gg;
            if (nn >= N) break;
            float t = cs[gg] + bias;
            if (lane < 32)
                __builtin_nontemporal_store(t, &out[(size_t)nn * 32 + lane]);
            else
                __builtin_nontemporal_store(t, &out[(size_t)N * 32 + (size_t)nn * 32 + (lane - 32)]);
        }
    }
}

extern "C" void kernel_launch(void* const* d_in, const int* in_sizes, int n_in,
                              void* d_out, int out_size, void* d_ws, size_t ws_size,
                              hipStream_t stream) {
    const float* x   = (const float*)d_in[0];
    const int*   ei  = (const int*)d_in[1];
    const float* W1  = (const float*)d_in[2];
    const float* b1  = (const float*)d_in[3];
    const float* Wmu = (const float*)d_in[4];
    const float* bmu = (const float*)d_in[5];
    const float* Wls = (const float*)d_in[6];
    const float* bls = (const float*)d_in[7];
    float* out = (float*)d_out;

    const int N = in_sizes[0] / 128;          // 50000  (< 65536: u16 src pack)
    const int E = in_sizes[1] / 2;            // 800000
    const int* src = ei;
    const int* dst = ei + E;
    const int SB    = (E + 2047) / 2048;      // scatter blocks (391)
    const int NBUCK = (N + 255) / 256;        // buckets (196)
    const int NG    = (N + 31) / 32;          // gather blocks (32 nodes/block)
    const int ECAP  = NBUCK * CAPB;           // edges array capacity

    char* w = (char*)d_ws;
    auto carve = [&](size_t bytes) { char* p = w; w += (bytes + 1023) & ~(size_t)1023; return p; };
    int*    cmat    = (int*)   carve((size_t)SB * 256 * 4);            // counts
    uint*   recs    = (uint*)  carve((size_t)NBUCK * SB * CAPC * 4);   // cells
    int*    rp2     = (int*)   carve((size_t)NBUCK * 257 * 4);         // row_ptr
    float*  dinv    = (float*) carve((size_t)N * 4);
    ushort* edges   = (ushort*)carve((size_t)ECAP * 2);          // u16 src recs
    ushort* hpA     = (ushort*)carve((size_t)N * 32 * 2);        // feats 0-31
    ushort* hpB     = (ushort*)carve((size_t)N * 32 * 2);        // feats 32-63
    ushort* midA    = (ushort*)carve((size_t)N * 32 * 2);
    ushort* midB    = (ushort*)carve((size_t)N * 32 * 2);

    k_scatter <<<SB, 256, 0, stream>>>(src, dst, cmat, recs, E, SB);
    k_phaseBG <<<NBUCK, 256, 0, stream>>>(recs, cmat, x, W1, rp2, dinv,
                                          edges, hpA, hpB, N, NBUCK, SB);
    k_gather1 <<<NG, 256, 0, stream>>>((const uint*)hpA, (const uint*)hpB,
                                       rp2, edges, dinv, b1,
                                       (uint*)midA, (uint*)midB, N, ECAP);
    k_gather2 <<<NG, 256, 0, stream>>>((const uint*)midA, (const uint*)midB,
                                       rp2, edges, dinv,
                                       Wmu, Wls, bmu, bls, out, N, ECAP);
}

// Round 10
// 167.089 us; speedup vs baseline: 2.5216x; 1.2424x over previous
//
#include <hip/hip_runtime.h>
#include <hip/hip_fp16.h>
#include <math.h>

// ---------------------------------------------------------------------------
// VariationalGCNEncoder: N=50000, E=800000, 128 -> 64 -> {32,32}
// R20: decomposition round. R19b evidence: phaseBG=60.7us (latency-bound;
//      nt-loads bypassed L2 in the cell copy; gemm trapped at 196-block
//      occupancy), gather half-split regressed ~35us (uint2 loads + doubled
//      edge reads; L2-residency theory refuted twice now).
//      (a) gathers reverted to R16's best-measured form (uint4, single
//          128B-row arrays, no nt hints; rp2 per-bucket row_ptr indexing).
//      (b) gemm split back out (782 blocks, 4/CU occupancy, R14 form).
//      (c) phaseB CSR-only; cell copy vectorized uint4 (18 rolled iterations
//          vs 73) with NORMAL loads (L2-hot).
//      Scatter (deterministic cells, no memset) kept. 5 dispatches.
// Pipeline:
//   scatter -> phaseB(CSR: rp2,dinv,edges) -> gemm -> gather1 -> gather2
// ---------------------------------------------------------------------------

typedef unsigned int uint;
typedef unsigned short ushort;
typedef __attribute__((ext_vector_type(8))) short short8;   // 8 bf16 = 4 VGPR
typedef __attribute__((ext_vector_type(4))) float f32x4;    // MFMA acc

#define CAPC 48     // per (scatter-block,bucket) cell capacity (~1e-12 tail)
#define CAPB 5120   // per-bucket edge region (mean 4096, sigma 64)

__device__ __forceinline__ ushort f2bf(float x) {          // f32 -> bf16 RNE
    uint u = __float_as_uint(x);
    u += 0x7fffu + ((u >> 16) & 1u);
    return (ushort)(u >> 16);
}
__device__ __forceinline__ float bf2f(ushort h) {
    return __uint_as_float((uint)h << 16);
}

// ---- scatter: deterministic per-(block,bucket) cells, no memset needed ----
// rec = src(16) | dstlow(8)<<16 | bucket(8)<<24 ; bucket = dst>>8
__global__ __launch_bounds__(256) void k_scatter(
        const int* __restrict__ src, const int* __restrict__ dst,
        int* __restrict__ cmat, uint* __restrict__ recs, int E, int SB) {
    __shared__ int h[256];
    const int tid = threadIdx.x;
    const int bx  = blockIdx.x;
    h[tid] = 0;
    __syncthreads();
    const int base = bx * 2048;
    uint rec[8]; int rk[8];
    #pragma unroll
    for (int k = 0; k < 8; ++k) {
        int i = base + k * 256 + tid;
        if (i < E) {
            int s = __builtin_nontemporal_load(src + i);
            int d = __builtin_nontemporal_load(dst + i);
            int b = d >> 8;
            rec[k] = (uint)s | ((uint)(d & 255) << 16) | ((uint)b << 24);
            rk[k] = atomicAdd(&h[b], 1);
        }
    }
    __syncthreads();
    cmat[bx * 256 + tid] = h[tid];            // always written (no poison)
    #pragma unroll
    for (int k = 0; k < 8; ++k) {
        int i = base + k * 256 + tid;
        if (i < E) {
            int b = rec[k] >> 24;
            if (rk[k] < CAPC)
                recs[((size_t)b * SB + bx) * CAPC + rk[k]] = rec[k];
        }
    }
}

// ---- phaseB: CSR finish only. One block per bucket (256 contiguous nodes).
// 1. cell counts one-per-thread (parallel), LDS 512-scan -> offsets/total.
// 2. uint4 cell copy (normal loads; CAPC=48 -> 12 uint4/cell) + dstlow hist.
// 3. dstlow scan -> rp2 + dinv; u16 edge emit into edges[bx*CAPB..].
__global__ __launch_bounds__(256, 4) void k_phaseB(
        const uint* __restrict__ recs, const int* __restrict__ cmat,
        int* __restrict__ rp2, float* __restrict__ dinv,
        ushort* __restrict__ edges, int N, int NBUCK, int SB) {
    __shared__ int h[256];
    __shared__ int p[256];
    __shared__ int cc[512];
    __shared__ int co[512];
    __shared__ int lowTot, scnt;
    __shared__ uint rstage[CAPB];               // 20KB
    const int tid = threadIdx.x;
    const int bx  = blockIdx.x;
    h[tid] = 0;
    // -- 1. cell counts (parallel loads) + 512-scan -------------------------
    cc[tid]       = (tid < SB)       ? min(cmat[tid * 256 + bx], CAPC) : 0;
    cc[tid + 256] = (tid + 256 < SB) ? min(cmat[(tid + 256) * 256 + bx], CAPC) : 0;
    __syncthreads();
    int v = cc[tid];
    p[tid] = v;
    __syncthreads();
    #pragma unroll
    for (int off = 1; off < 256; off <<= 1) {
        int xv = (tid >= off) ? p[tid - off] : 0;
        __syncthreads();
        p[tid] += xv;
        __syncthreads();
    }
    co[tid] = p[tid] - v;
    if (tid == 255) lowTot = p[255];
    __syncthreads();
    v = cc[tid + 256];
    p[tid] = v;
    __syncthreads();
    #pragma unroll
    for (int off = 1; off < 256; off <<= 1) {
        int xv = (tid >= off) ? p[tid - off] : 0;
        __syncthreads();
        p[tid] += xv;
        __syncthreads();
    }
    co[tid + 256] = p[tid] - v + lowTot;
    if (tid == 255) scnt = lowTot + p[255];
    __syncthreads();
    // -- 2. uint4 cell copy (L2 loads, 4 recs per iteration) ----------------
    const int TOTS4 = SB * (CAPC / 4);          // 12 uint4 per cell
    for (int s4 = tid; s4 < TOTS4; s4 += 256) {
        const int sb = s4 / (CAPC / 4);
        const int i0 = (s4 - sb * (CAPC / 4)) * 4;
        const int c  = cc[sb];
        if (i0 < c) {
            const uint4 r4 = *(const uint4*)(recs +
                                 ((size_t)bx * SB + sb) * CAPC + i0);
            const int d0 = co[sb] + i0;
            const int nv = min(c - i0, 4);
            uint rr[4] = {r4.x, r4.y, r4.z, r4.w};
            #pragma unroll
            for (int j = 0; j < 4; ++j) {
                if (j < nv && d0 + j < CAPB) {
                    rstage[d0 + j] = rr[j];
                    atomicAdd(&h[(rr[j] >> 16) & 255], 1);
                }
            }
        }
    }
    __syncthreads();
    // -- 3. dstlow scan -> rp2/dinv; edge emit ------------------------------
    v = h[tid];
    p[tid] = v;
    __syncthreads();
    #pragma unroll
    for (int off = 1; off < 256; off <<= 1) {
        int xv = (tid >= off) ? p[tid - off] : 0;
        __syncthreads();
        p[tid] += xv;
        __syncthreads();
    }
    const int excl = p[tid] - v;
    const int node = bx * 256 + tid;
    rp2[bx * 257 + tid] = bx * CAPB + excl;
    if (tid == 255) rp2[bx * 257 + 256] = bx * CAPB + excl + v;
    if (node < N) dinv[node] = rsqrtf((float)(v + 1));
    h[tid] = excl;                              // reuse as local cursor
    __syncthreads();
    const int cnt = min(scnt, CAPB);
    for (int i = tid; i < cnt; i += 256) {
        uint r = rstage[i];
        int pos = atomicAdd(&h[(r >> 16) & 255], 1);
        if (pos < CAPB)
            edges[(size_t)bx * CAPB + pos] = (ushort)(r & 0xffffu);
    }
}

// ---- MFMA gemm, W1 staged transposed/bf16 in LDS (R14 form, 782 blocks) ----
__global__ __launch_bounds__(256, 4) void k_gemm(
        const float* __restrict__ x, const float* __restrict__ W1,
        const float* __restrict__ dinv, ushort* __restrict__ hp, int N) {
    __shared__ ushort Wt[64][136];   // col-major bf16, row stride 272B
    const int tid = threadIdx.x;
    #pragma unroll
    for (int it = 0; it < 8; ++it) {           // 8192 elems, 32/thread
        int idx = (it * 256 + tid) * 4;
        int k = idx >> 6, c = idx & 63;
        float4 wv = *(const float4*)(W1 + idx);
        Wt[c + 0][k] = f2bf(wv.x);
        Wt[c + 1][k] = f2bf(wv.y);
        Wt[c + 2][k] = f2bf(wv.z);
        Wt[c + 3][k] = f2bf(wv.w);
    }
    __syncthreads();
    const int w = tid >> 6, l = tid & 63;
    const int m = l & 15, q = l >> 4;
    const int row0 = blockIdx.x * 64 + w * 16;
    const size_t arow = (size_t)min(row0 + m, N - 1);
    f32x4 acc0 = {0.f, 0.f, 0.f, 0.f}, acc1 = acc0, acc2 = acc0, acc3 = acc0;
    #pragma unroll
    for (int kc = 0; kc < 4; ++kc) {
        const int kofs = kc * 32 + q * 8;
        const float4* xr = (const float4*)(x + arow * 128 + kofs);
        float4 xa = xr[0], xb = xr[1];
        short8 a;
        a[0] = (short)f2bf(xa.x); a[1] = (short)f2bf(xa.y);
        a[2] = (short)f2bf(xa.z); a[3] = (short)f2bf(xa.w);
        a[4] = (short)f2bf(xb.x); a[5] = (short)f2bf(xb.y);
        a[6] = (short)f2bf(xb.z); a[7] = (short)f2bf(xb.w);
        short8 b0 = *(const short8*)&Wt[m][kofs];
        short8 b1 = *(const short8*)&Wt[m + 16][kofs];
        short8 b2 = *(const short8*)&Wt[m + 32][kofs];
        short8 b3 = *(const short8*)&Wt[m + 48][kofs];
        acc0 = __builtin_amdgcn_mfma_f32_16x16x32_bf16(a, b0, acc0, 0, 0, 0);
        acc1 = __builtin_amdgcn_mfma_f32_16x16x32_bf16(a, b1, acc1, 0, 0, 0);
        acc2 = __builtin_amdgcn_mfma_f32_16x16x32_bf16(a, b2, acc2, 0, 0, 0);
        acc3 = __builtin_amdgcn_mfma_f32_16x16x32_bf16(a, b3, acc3, 0, 0, 0);
    }
    #pragma unroll
    for (int r = 0; r < 4; ++r) {              // D: row=q*4+r, col=g*16+m
        int row = row0 + q * 4 + r;
        if (row >= N) continue;
        float dv = dinv[row];
        ushort* hr = hp + (size_t)row * 64 + m;
        hr[0]  = f2bf(acc0[r] * dv);
        hr[16] = f2bf(acc1[r] * dv);
        hr[32] = f2bf(acc2[r] * dv);
        hr[48] = f2bf(acc3[r] * dv);
    }
}

// ---- 8-lane-group gather: group owns one node; lane owns 8 features ----
// Per 8-edge chunk: one coalesced edges load (2B/lane), then 8 row loads
// (8 lanes x uint4 = one 128B line each), all independent -> 8 rows in
// flight per group, 64 per wave. No cross-lane reduce (features disjoint).
__device__ __forceinline__ void gather_grp8(
        const uint* __restrict__ hp, const ushort* __restrict__ edges,
        int beg, int end, int ECAP, int sl, float4& a0, float4& a1) {
    for (int base = beg; base < end; base += 8) {
        const int mrec = (int)edges[min(base + sl, ECAP - 1)];
        const int cnt = end - base;
        if (cnt >= 8) {
            #pragma unroll
            for (int i = 0; i < 8; ++i) {
                const int r = __shfl(mrec, i, 8);
                const uint4 v = *(const uint4*)(hp + (size_t)r * 32 + 4 * sl);
                a0.x += __uint_as_float(v.x << 16);
                a0.y += __uint_as_float(v.x & 0xffff0000u);
                a0.z += __uint_as_float(v.y << 16);
                a0.w += __uint_as_float(v.y & 0xffff0000u);
                a1.x += __uint_as_float(v.z << 16);
                a1.y += __uint_as_float(v.z & 0xffff0000u);
                a1.z += __uint_as_float(v.w << 16);
                a1.w += __uint_as_float(v.w & 0xffff0000u);
            }
        } else {
            #pragma unroll
            for (int i = 0; i < 7; ++i) {     // cnt in 1..7; dups are L1 hits
                const int r = __shfl(mrec, min(i, cnt - 1), 8);
                uint4 v = *(const uint4*)(hp + (size_t)r * 32 + 4 * sl);
                if (i >= cnt) { v.x = 0u; v.y = 0u; v.z = 0u; v.w = 0u; }
                a0.x += __uint_as_float(v.x << 16);
                a0.y += __uint_as_float(v.x & 0xffff0000u);
                a0.z += __uint_as_float(v.y << 16);
                a0.w += __uint_as_float(v.y & 0xffff0000u);
                a1.x += __uint_as_float(v.z << 16);
                a1.y += __uint_as_float(v.z & 0xffff0000u);
                a1.z += __uint_as_float(v.w << 16);
                a1.w += __uint_as_float(v.w & 0xffff0000u);
            }
        }
    }
}

// hm[n] = dinv * relu( dinv * (sum hp[src] + hp[n]) + b1 )   (bf16x2)
__global__ __launch_bounds__(256, 6) void k_gather1(
        const uint* __restrict__ hp, const int* __restrict__ rp2,
        const ushort* __restrict__ edges, const float* __restrict__ dinv,
        const float* __restrict__ b1, uint* __restrict__ ho, int N, int ECAP) {
    const int lane = threadIdx.x & 63;
    const int sl = lane & 7;
    const int n = blockIdx.x * 32 + ((threadIdx.x >> 6) << 3) + (lane >> 3);
    const int nc = min(n, N - 1);
    const int beg = rp2[(nc >> 8) * 257 + (nc & 255)];
    const int end = rp2[(nc >> 8) * 257 + (nc & 255) + 1];
    float4 a0 = {0.f, 0.f, 0.f, 0.f}, a1 = a0;
    gather_grp8(hp, edges, beg, end, ECAP, sl, a0, a1);
    const float dv = dinv[nc];
    const uint4 sv = *(const uint4*)(hp + (size_t)nc * 32 + 4 * sl);  // self
    const float4 bA = ((const float4*)b1)[2 * sl];
    const float4 bB = ((const float4*)b1)[2 * sl + 1];
    float s0 = a0.x + bf2f((ushort)sv.x);
    float s1 = a0.y + bf2f((ushort)(sv.x >> 16));
    float s2 = a0.z + bf2f((ushort)sv.y);
    float s3 = a0.w + bf2f((ushort)(sv.y >> 16));
    float s4 = a1.x + bf2f((ushort)sv.z);
    float s5 = a1.y + bf2f((ushort)(sv.z >> 16));
    float s6 = a1.z + bf2f((ushort)sv.w);
    float s7 = a1.w + bf2f((ushort)(sv.w >> 16));
    float h0 = fmaxf(fmaf(dv, s0, bA.x), 0.f) * dv;   // relu then pre-scale
    float h1 = fmaxf(fmaf(dv, s1, bA.y), 0.f) * dv;
    float h2 = fmaxf(fmaf(dv, s2, bA.z), 0.f) * dv;
    float h3 = fmaxf(fmaf(dv, s3, bA.w), 0.f) * dv;
    float h4 = fmaxf(fmaf(dv, s4, bB.x), 0.f) * dv;
    float h5 = fmaxf(fmaf(dv, s5, bB.y), 0.f) * dv;
    float h6 = fmaxf(fmaf(dv, s6, bB.z), 0.f) * dv;
    float h7 = fmaxf(fmaf(dv, s7, bB.w), 0.f) * dv;
    if (n < N) {
        uint4 o;
        o.x = (uint)f2bf(h0) | ((uint)f2bf(h1) << 16);
        o.y = (uint)f2bf(h2) | ((uint)f2bf(h3) << 16);
        o.z = (uint)f2bf(h4) | ((uint)f2bf(h5) << 16);
        o.w = (uint)f2bf(h6) | ((uint)f2bf(h7) << 16);
        *(uint4*)(ho + (size_t)n * 32 + 4 * sl) = o;
    }
}

// g = dinv*(sum hm[src] + hm[n]);  out[n] = g @ [Wmu|Wls] + bias
__global__ __launch_bounds__(256, 6) void k_gather2(
        const uint* __restrict__ hp, const int* __restrict__ rp2,
        const ushort* __restrict__ edges, const float* __restrict__ dinv,
        const float* __restrict__ Wmu, const float* __restrict__ Wls,
        const float* __restrict__ bmu, const float* __restrict__ bls,
        float* __restrict__ out, int N, int ECAP) {
    __shared__ __align__(16) float hs[4][8][64];   // [wave][group-node][feat]
    const int lane = threadIdx.x & 63;
    const int sl = lane & 7, grp = lane >> 3;
    const int w = threadIdx.x >> 6;
    const int n = blockIdx.x * 32 + (w << 3) + grp;
    const int nc = min(n, N - 1);
    const int beg = rp2[(nc >> 8) * 257 + (nc & 255)];
    const int end = rp2[(nc >> 8) * 257 + (nc & 255) + 1];
    float4 a0 = {0.f, 0.f, 0.f, 0.f}, a1 = a0;
    gather_grp8(hp, edges, beg, end, ECAP, sl, a0, a1);
    const float dv = dinv[nc];
    const uint4 sv = *(const uint4*)(hp + (size_t)nc * 32 + 4 * sl);
    float4 gA, gB;
    gA.x = dv * (a0.x + bf2f((ushort)sv.x));
    gA.y = dv * (a0.y + bf2f((ushort)(sv.x >> 16)));
    gA.z = dv * (a0.z + bf2f((ushort)sv.y));
    gA.w = dv * (a0.w + bf2f((ushort)(sv.y >> 16)));
    gB.x = dv * (a1.x + bf2f((ushort)sv.z));
    gB.y = dv * (a1.y + bf2f((ushort)(sv.z >> 16)));
    gB.z = dv * (a1.z + bf2f((ushort)sv.w));
    gB.w = dv * (a1.w + bf2f((ushort)(sv.w >> 16)));
    *(float4*)&hs[w][grp][8 * sl]     = gA;        // wave-local LDS: no barrier
    *(float4*)&hs[w][grp][8 * sl + 4] = gB;
    // epilogue: out_row = g @ [Wmu|Wls] + bias for the wave's 8 nodes,
    // two passes of 4 nodes; W column loads hoisted; hs reads broadcast.
    const float* Wsel = (lane < 32) ? (Wmu + lane) : (Wls + (lane - 32));
    const float bias  = (lane < 32) ? bmu[lane] : bls[lane - 32];
    #pragma unroll
    for (int p = 0; p < 2; ++p) {
        float c0 = 0.f, c1 = 0.f, c2 = 0.f, c3 = 0.f;
        #pragma unroll 4
        for (int k = 0; k < 64; ++k) {
            float wv = Wsel[k * 32];
            c0 = fmaf(hs[w][p * 4 + 0][k], wv, c0);
            c1 = fmaf(hs[w][p * 4 + 1][k], wv, c1);
            c2 = fmaf(hs[w][p * 4 + 2][k], wv, c2);
            c3 = fmaf(hs[w][p * 4 + 3][k], wv, c3);
        }
        const int n0 = blockIdx.x * 32 + (w << 3) + p * 4;
        float cs[4] = {c0, c1, c2, c3};
        #pragma unroll
        for (int gg = 0; gg < 4; ++gg) {
            int nn = n0 + gg;
            if (nn >= N) break;
            float t = cs[gg] + bias;
            if (lane < 32) out[(size_t)nn * 32 + lane] = t;
            else           out[(size_t)N * 32 + (size_t)nn * 32 + (lane - 32)] = t;
        }
    }
}

extern "C" void kernel_launch(void* const* d_in, const int* in_sizes, int n_in,
                              void* d_out, int out_size, void* d_ws, size_t ws_size,
                              hipStream_t stream) {
    const float* x   = (const float*)d_in[0];
    const int*   ei  = (const int*)d_in[1];
    const float* W1  = (const float*)d_in[2];
    const float* b1  = (const float*)d_in[3];
    const float* Wmu = (const float*)d_in[4];
    const float* bmu = (const float*)d_in[5];
    const float* Wls = (const float*)d_in[6];
    const float* bls = (const float*)d_in[7];
    float* out = (float*)d_out;

    const int N = in_sizes[0] / 128;          // 50000  (< 65536: u16 src pack)
    const int E = in_sizes[1] / 2;            // 800000
    const int* src = ei;
    const int* dst = ei + E;
    const int SB    = (E + 2047) / 2048;      // scatter blocks (391)
    const int NBUCK = (N + 255) / 256;        // buckets (196)
    const int GB    = (N + 63) / 64;          // gemm row-tile blocks (782)
    const int NG    = (N + 31) / 32;          // gather blocks (32 nodes/block)
    const int ECAP  = NBUCK * CAPB;           // edges array capacity

    char* w = (char*)d_ws;
    auto carve = [&](size_t bytes) { char* p = w; w += (bytes + 1023) & ~(size_t)1023; return p; };
    int*    cmat    = (int*)   carve((size_t)SB * 256 * 4);            // counts
    uint*   recs    = (uint*)  carve((size_t)NBUCK * SB * CAPC * 4);   // cells
    int*    rp2     = (int*)   carve((size_t)NBUCK * 257 * 4);         // row_ptr
    float*  dinv    = (float*) carve((size_t)N * 4);
    ushort* edges   = (ushort*)carve((size_t)ECAP * 2);          // u16 src recs
    ushort* h_pre   = (ushort*)carve((size_t)N * 64 * 2);        // bf16 pre-scaled
    ushort* h_mid   = (ushort*)carve((size_t)N * 64 * 2);        // bf16 pre-scaled

    k_scatter <<<SB, 256, 0, stream>>>(src, dst, cmat, recs, E, SB);
    k_phaseB  <<<NBUCK, 256, 0, stream>>>(recs, cmat, rp2, dinv, edges,
                                          N, NBUCK, SB);
    k_gemm    <<<GB, 256, 0, stream>>>(x, W1, dinv, h_pre, N);
    k_gather1 <<<NG, 256, 0, stream>>>((const uint*)h_pre, rp2, edges, dinv,
                                       b1, (uint*)h_mid, N, ECAP);
    k_gather2 <<<NG, 256, 0, stream>>>((const uint*)h_mid, rp2, edges, dinv,
                                       Wmu, Wls, bmu, bls, out, N, ECAP);
}